// Round 3
// baseline (307.578 us; speedup 1.0000x reference)
//
#include <hip/hip_runtime.h>
#include <hip/hip_bf16.h>
#include <stdint.h>

#define S_LEN 4096

typedef short s16x8  __attribute__((ext_vector_type(8)));
typedef float f32x4  __attribute__((ext_vector_type(4)));
typedef float f32x16 __attribute__((ext_vector_type(16)));

// log2(e)/8 : folded into Q at QKV epilogue; attn does exp2(score) directly
#define CEXP 0.18033688011112042f

__device__ __forceinline__ unsigned short f2bf(float f) {
    union { float f; unsigned u; } v; v.f = f;
    unsigned r = v.u + 0x7fffu + ((v.u >> 16) & 1u);
    return (unsigned short)(r >> 16);
}

__device__ __forceinline__ ushort2 pkbf(float a, float b) {
    float2 f; f.x = a; f.y = b;
    __hip_bfloat162 h = __float22bfloat162_rn(f);
    union { __hip_bfloat162 h; ushort2 u; } cv; cv.h = h;
    return cv.u;
}

__device__ __forceinline__ ushort4 pkbf4(float x, float y, float z, float w) {
    ushort2 lo = pkbf(x, y), hi = pkbf(z, w);
    ushort4 r; r.x = lo.x; r.y = lo.y; r.z = hi.x; r.w = hi.y;
    return r;
}

typedef const __attribute__((address_space(1))) void* gas_t;
typedef __attribute__((address_space(3))) void* sas_t;

__device__ __forceinline__ void async16(const void* g, void* s) {
    __builtin_amdgcn_global_load_lds((gas_t)g, (sas_t)s, 16, 0, 0);
}

// ---------------------------------------------------------------------------
// fp32 -> bf16 convert for X (4194304) and W (3145728). 8 elems/thread.
// ---------------------------------------------------------------------------
__global__ __launch_bounds__(256) void cvt_bf16(
    const float* __restrict__ X, const float* __restrict__ W,
    unsigned short* __restrict__ Xb, unsigned short* __restrict__ Wb)
{
    const long NX = 4194304;
    long i = (long)(blockIdx.x * 256 + threadIdx.x) * 8;
    const float* src; unsigned short* dst; long off;
    if (i < NX) { src = X; dst = Xb; off = i; }
    else        { src = W; dst = Wb; off = i - NX; }
    float4 a = *(const float4*)(src + off);
    float4 b = *(const float4*)(src + off + 4);
    union { s16x8 v; ushort4 q[2]; } o;
    o.q[0] = pkbf4(a.x, a.y, a.z, a.w);
    o.q[1] = pkbf4(b.x, b.y, b.z, b.w);
    *(s16x8*)(dst + off) = o.v;
}

// ---------------------------------------------------------------------------
// Kernel A (primary): qkv = Xb @ Wb^T + b, bf16 in, m97-style staging.
// 128x128 tile, BK=64, global_load_lds width-16, mfma 16x16x32.
// XCD-swizzled 1-D grid (768): each XCD owns 3 bn-strips (Wb 0.75MB stays in
// its L2); 3 consecutive same-XCD blocks share one Xb tile.
// Q is pre-scaled by CEXP. Q,K -> [h][s][d]; V -> transposed [h][d][s].
// ---------------------------------------------------------------------------
__global__ __launch_bounds__(256) void qkv_gemm_bf16(
    const unsigned short* __restrict__ Xb, const unsigned short* __restrict__ Wb,
    const float* __restrict__ bias,
    unsigned short* __restrict__ Qb, unsigned short* __restrict__ Kb,
    unsigned short* __restrict__ Vt)
{
    __shared__ __align__(16) unsigned short sm[17408];   // 34816 B
    unsigned short* As = sm;            // [128][64] bf16, unpadded (async dst)
    unsigned short* Bs = sm + 8192;     // [128][64]

    const int t = threadIdx.x;
    const int l = t & 63;
    const int w = t >> 6;
    // XCD-aware swizzle: xcd = bid%8 owns bn in {3*xcd .. 3*xcd+2}
    const int bid = blockIdx.x;
    const int xcd = bid & 7;
    const int ii  = bid >> 3;          // 0..95
    const int bn  = 3 * xcd + (ii % 3);
    const int bm  = ii / 3;
    const int rowBase = (w >> 1) * 64;
    const int colBase = (w & 1) * 64;

    f32x4 acc[4][4];
#pragma unroll
    for (int i = 0; i < 4; i++)
#pragma unroll
        for (int j = 0; j < 4; j++) acc[i][j] = (f32x4)0.f;

    const int srow = l >> 3;        // 0..7
    const int scol = (l & 7) * 8;   // shorts

    for (int kt = 0; kt < 16; ++kt) {
        const int k0 = kt * 64;
#pragma unroll
        for (int c = 0; c < 4; ++c) {
            int m = w * 4 + c;                    // chunk 0..15 (8 rows each)
            const unsigned short* ga = Xb + (bm * 128 + m * 8 + srow) * 1024 + k0 + scol;
            const unsigned short* gb = Wb + (bn * 128 + m * 8 + srow) * 1024 + k0 + scol;
            async16(ga, As + m * 512);
            async16(gb, Bs + m * 512);
        }
        __syncthreads();

#pragma unroll
        for (int kc = 0; kc < 2; ++kc) {
            s16x8 af[4], bf[4];
#pragma unroll
            for (int i = 0; i < 4; i++) {
                af[i] = *(const s16x8*)(As + (rowBase + i * 16 + (l & 15)) * 64 + kc * 32 + (l >> 4) * 8);
                bf[i] = *(const s16x8*)(Bs + (colBase + i * 16 + (l & 15)) * 64 + kc * 32 + (l >> 4) * 8);
            }
#pragma unroll
            for (int i = 0; i < 4; i++)
#pragma unroll
                for (int j = 0; j < 4; j++)
                    acc[i][j] = __builtin_amdgcn_mfma_f32_16x16x32_bf16(af[i], bf[j], acc[i][j], 0, 0, 0);
        }
        __syncthreads();
    }

    if (bn < 16) {
#pragma unroll
        for (int j = 0; j < 4; j++) {
            int col = bn * 128 + colBase + j * 16 + (l & 15);
            float bv = bias[col];
            int region = col >> 10;            // 0=Q, 1=K
            int within = col & 1023;
            int h = within >> 6, d = within & 63;
            unsigned short* dst = (region == 0) ? Qb : Kb;
            float scl = (region == 0) ? CEXP : 1.0f;
#pragma unroll
            for (int i = 0; i < 4; i++) {
                int s0 = bm * 128 + rowBase + i * 16 + ((l >> 4) << 2);
#pragma unroll
                for (int r = 0; r < 4; r++)
                    dst[(h * S_LEN + s0 + r) * 64 + d] = f2bf((acc[i][j][r] + bv) * scl);
            }
        }
    } else {
        __syncthreads();
        unsigned short* Lt = sm;              // 128 x 136
#pragma unroll
        for (int j = 0; j < 4; j++) {
            int cl = colBase + j * 16 + (l & 15);
            float bv = bias[bn * 128 + cl];
#pragma unroll
            for (int i = 0; i < 4; i++) {
                int s0 = rowBase + i * 16 + ((l >> 4) << 2);
                *(ushort4*)(Lt + cl * 136 + s0) =
                    pkbf4(acc[i][j][0] + bv, acc[i][j][1] + bv,
                          acc[i][j][2] + bv, acc[i][j][3] + bv);
            }
        }
        __syncthreads();
#pragma unroll
        for (int p = 0; p < 8; ++p) {
            int dl  = (t >> 4) + p * 16;
            int sch = (t & 15) * 8;
            int o = bn * 128 + dl - 2048;
            int h = o >> 6, d = o & 63;
            s16x8 v = *(const s16x8*)(Lt + dl * 136 + sch);
            *(s16x8*)(Vt + (h * 64 + d) * S_LEN + bm * 128 + sch) = v;
        }
    }
}

// ---------------------------------------------------------------------------
// Kernel A (fallback, small ws): fp32-staged GEMM
// ---------------------------------------------------------------------------
__global__ __launch_bounds__(256) void qkv_gemm_f32(
    const float* __restrict__ X, const float* __restrict__ W,
    const float* __restrict__ bias,
    unsigned short* __restrict__ Qb, unsigned short* __restrict__ Kb,
    unsigned short* __restrict__ Vt)
{
    __shared__ __align__(16) unsigned short sm[17408];
    unsigned short* As = sm;
    unsigned short* Bs = sm + 5120;

    const int t = threadIdx.x;
    const int l = t & 63;
    const int w = t >> 6;
    const int bm = blockIdx.y, bn = blockIdx.x;
    const int rowBase = (w >> 1) * 64;
    const int colBase = (w & 1) * 64;

    f32x4 acc[4][4];
#pragma unroll
    for (int i = 0; i < 4; i++)
#pragma unroll
        for (int j = 0; j < 4; j++) acc[i][j] = (f32x4)0.f;

    const int sr = t >> 3;
    const int sc = (t & 7) * 4;

    for (int kt = 0; kt < 32; ++kt) {
        const int k0 = kt * 32;
#pragma unroll
        for (int p = 0; p < 4; ++p) {
            int r = sr + p * 32;
            float4 xa = *(const float4*)(X + (bm * 128 + r) * 1024 + k0 + sc);
            float4 wb = *(const float4*)(W + (bn * 128 + r) * 1024 + k0 + sc);
            *(ushort4*)(As + r * 40 + sc) = pkbf4(xa.x, xa.y, xa.z, xa.w);
            *(ushort4*)(Bs + r * 40 + sc) = pkbf4(wb.x, wb.y, wb.z, wb.w);
        }
        __syncthreads();

        s16x8 af[4], bf[4];
#pragma unroll
        for (int i = 0; i < 4; i++) {
            af[i] = *(const s16x8*)(As + (rowBase + i * 16 + (l & 15)) * 40 + (l >> 4) * 8);
            bf[i] = *(const s16x8*)(Bs + (colBase + i * 16 + (l & 15)) * 40 + (l >> 4) * 8);
        }
#pragma unroll
        for (int i = 0; i < 4; i++)
#pragma unroll
            for (int j = 0; j < 4; j++)
                acc[i][j] = __builtin_amdgcn_mfma_f32_16x16x32_bf16(af[i], bf[j], acc[i][j], 0, 0, 0);
        __syncthreads();
    }

    if (bn < 16) {
#pragma unroll
        for (int j = 0; j < 4; j++) {
            int col = bn * 128 + colBase + j * 16 + (l & 15);
            float bv = bias[col];
            int region = col >> 10;
            int within = col & 1023;
            int h = within >> 6, d = within & 63;
            unsigned short* dst = (region == 0) ? Qb : Kb;
            float scl = (region == 0) ? CEXP : 1.0f;
#pragma unroll
            for (int i = 0; i < 4; i++) {
                int s0 = bm * 128 + rowBase + i * 16 + ((l >> 4) << 2);
#pragma unroll
                for (int r = 0; r < 4; r++)
                    dst[(h * S_LEN + s0 + r) * 64 + d] = f2bf((acc[i][j][r] + bv) * scl);
            }
        }
    } else {
        __syncthreads();
        unsigned short* Lt = sm;
#pragma unroll
        for (int j = 0; j < 4; j++) {
            int cl = colBase + j * 16 + (l & 15);
            float bv = bias[bn * 128 + cl];
#pragma unroll
            for (int i = 0; i < 4; i++) {
                int s0 = rowBase + i * 16 + ((l >> 4) << 2);
                *(ushort4*)(Lt + cl * 136 + s0) =
                    pkbf4(acc[i][j][0] + bv, acc[i][j][1] + bv,
                          acc[i][j][2] + bv, acc[i][j][3] + bv);
            }
        }
        __syncthreads();
#pragma unroll
        for (int p = 0; p < 8; ++p) {
            int dl  = (t >> 4) + p * 16;
            int sch = (t & 15) * 8;
            int o = bn * 128 + dl - 2048;
            int h = o >> 6, d = o & 63;
            s16x8 v = *(const s16x8*)(Lt + dl * 136 + sch);
            *(s16x8*)(Vt + (h * 64 + d) * S_LEN + bm * 128 + sch) = v;
        }
    }
}

// ---------------------------------------------------------------------------
// Kernel B: flash attention, S^T trick, fixed m=0 (scores bounded), kv-split
// x2 for occupancy (4 blocks/CU), XCD swizzle (each XCD owns 2 heads -> K+V
// 2MB stays L2-resident). Emits UNNORMALIZED O via atomicAdd into out, and
// row sums l via atomicAdd; norm_out applies tdiag/l afterwards.
// ---------------------------------------------------------------------------
__global__ __launch_bounds__(256, 4) void attn(
    const unsigned short* __restrict__ Qb, const unsigned short* __restrict__ Kb,
    const unsigned short* __restrict__ Vt,
    float* __restrict__ out, float* __restrict__ lsum)
{
    __shared__ __align__(16) unsigned short sm[17920];   // 35840 B
    unsigned short* Ks  = sm;            // 64 x 72 : [kv][d]
    unsigned short* Vts = sm + 4608;     // 64 x 72 : [d][kv]
    unsigned short* Ps  = sm + 9216;     // 4 waves x 32 x 68 : [q][kv]

    const int t = threadIdx.x;
    const int l = t & 63;
    const int w = t >> 6;
    // swizzle: xcd = bid%8 owns heads {2*xcd, 2*xcd+1}, both kv halves
    const int bid = blockIdx.x;
    const int xcd = bid & 7;
    const int ii  = bid >> 3;            // 0..127
    const int combo = xcd * 4 + (ii & 3);  // 0..31
    const int h   = combo >> 1;
    const int kvs = combo & 1;
    const int qbk = ii >> 2;             // 0..31
    const int qbase = qbk * 128 + w * 32;
    const int l31 = l & 31;
    const int lh  = l >> 5;

    s16x8 qf[4];
#pragma unroll
    for (int ks = 0; ks < 4; ks++)
        qf[ks] = *(const s16x8*)(Qb + (h * S_LEN + qbase + l31) * 64 + ks * 16 + lh * 8);

    f32x16 O0 = (f32x16)0.f, O1 = (f32x16)0.f;
    float lp0 = 0.f, lp1 = 0.f, lp2 = 0.f, lp3 = 0.f;

    const int strow = t >> 2;
    const int stch  = (t & 3) * 16;

    unsigned short* Pw = Ps + w * 2176 + l31 * 68;

    for (int kt = 0; kt < 32; ++kt) {
        const int kv0 = kvs * 2048 + kt * 64;
        {
            const unsigned short* ksrc = Kb + (h * S_LEN + kv0 + strow) * 64 + stch;
            const unsigned short* vsrc = Vt + (h * 64 + strow) * S_LEN + kv0 + stch;
            s16x8 k0v = *(const s16x8*)(ksrc);
            s16x8 k1v = *(const s16x8*)(ksrc + 8);
            s16x8 v0v = *(const s16x8*)(vsrc);
            s16x8 v1v = *(const s16x8*)(vsrc + 8);
            *(s16x8*)(Ks  + strow * 72 + stch)     = k0v;
            *(s16x8*)(Ks  + strow * 72 + stch + 8) = k1v;
            *(s16x8*)(Vts + strow * 72 + stch)     = v0v;
            *(s16x8*)(Vts + strow * 72 + stch + 8) = v1v;
        }
        __syncthreads();

        // S^T[kv][q] = K x Q^T  (scores pre-scaled via Q)
        f32x16 S0 = (f32x16)0.f, S1 = (f32x16)0.f;
#pragma unroll
        for (int ks = 0; ks < 4; ks++) {
            s16x8 a0 = *(const s16x8*)(Ks + l31 * 72 + ks * 16 + lh * 8);
            s16x8 a1 = *(const s16x8*)(Ks + (32 + l31) * 72 + ks * 16 + lh * 8);
            S0 = __builtin_amdgcn_mfma_f32_32x32x16_bf16(a0, qf[ks], S0, 0, 0, 0);
            S1 = __builtin_amdgcn_mfma_f32_32x32x16_bf16(a1, qf[ks], S1, 0, 0, 0);
        }

#pragma unroll
        for (int i = 0; i < 16; i += 4) {
            float p0 = __builtin_amdgcn_exp2f(S0[i+0]); S0[i+0] = p0; lp0 += p0;
            float p1 = __builtin_amdgcn_exp2f(S0[i+1]); S0[i+1] = p1; lp1 += p1;
            float p2 = __builtin_amdgcn_exp2f(S0[i+2]); S0[i+2] = p2; lp2 += p2;
            float p3 = __builtin_amdgcn_exp2f(S0[i+3]); S0[i+3] = p3; lp3 += p3;
        }
#pragma unroll
        for (int i = 0; i < 16; i += 4) {
            float p0 = __builtin_amdgcn_exp2f(S1[i+0]); S1[i+0] = p0; lp0 += p0;
            float p1 = __builtin_amdgcn_exp2f(S1[i+1]); S1[i+1] = p1; lp1 += p1;
            float p2 = __builtin_amdgcn_exp2f(S1[i+2]); S1[i+2] = p2; lp2 += p2;
            float p3 = __builtin_amdgcn_exp2f(S1[i+3]); S1[i+3] = p3; lp3 += p3;
        }

#pragma unroll
        for (int g = 0; g < 4; ++g) {
            *(ushort4*)(Pw + g * 8 + lh * 4)      = pkbf4(S0[g*4], S0[g*4+1], S0[g*4+2], S0[g*4+3]);
            *(ushort4*)(Pw + 32 + g * 8 + lh * 4) = pkbf4(S1[g*4], S1[g*4+1], S1[g*4+2], S1[g*4+3]);
        }

#pragma unroll
        for (int ks = 0; ks < 4; ks++) {
            union { s16x8 v; ushort4 q[2]; } pu;
            pu.q[0] = *(const ushort4*)(Pw + ks * 16 + lh * 8);
            pu.q[1] = *(const ushort4*)(Pw + ks * 16 + lh * 8 + 4);
            s16x8 av0 = *(const s16x8*)(Vts + l31 * 72 + ks * 16 + lh * 8);
            s16x8 av1 = *(const s16x8*)(Vts + (32 + l31) * 72 + ks * 16 + lh * 8);
            O0 = __builtin_amdgcn_mfma_f32_32x32x16_bf16(av0, pu.v, O0, 0, 0, 0);
            O1 = __builtin_amdgcn_mfma_f32_32x32x16_bf16(av1, pu.v, O1, 0, 0, 0);
        }
        __syncthreads();
    }

    // partial l for q = qbase + l31 (both lane-halves agree after shfl)
    float l_part = (lp0 + lp1) + (lp2 + lp3);
    float l_tot = l_part + __shfl_xor(l_part, 32);
    if (lh == 0) atomicAdd(lsum + h * S_LEN + qbase + l31, l_tot);

    // epilogue: LDS transpose of raw O, then coalesced atomicAdd into out
    __syncthreads();
    float* Lo = (float*)sm + w * 2176;   // 32 x 68 fp32 per wave
#pragma unroll
    for (int dt = 0; dt < 2; ++dt) {
        const f32x16& Ox = dt ? O1 : O0;
#pragma unroll
        for (int g = 0; g < 4; ++g) {
            int d0 = dt * 32 + g * 8 + lh * 4;
            float4 vv;
            vv.x = Ox[g*4+0]; vv.y = Ox[g*4+1]; vv.z = Ox[g*4+2]; vv.w = Ox[g*4+3];
            *(float4*)(Lo + l31 * 68 + d0) = vv;
        }
    }
    __syncthreads();
#pragma unroll
    for (int it = 0; it < 8; ++it) {
        int ql = it * 4 + (l >> 4);
        float4 vv = *(const float4*)(Lo + ql * 68 + (l & 15) * 4);
        float* dst = out + (qbase + ql) * 1024 + h * 64 + (l & 15) * 4;
        atomicAdd(dst + 0, vv.x);
        atomicAdd(dst + 1, vv.y);
        atomicAdd(dst + 2, vv.z);
        atomicAdd(dst + 3, vv.w);
    }
}

// ---------------------------------------------------------------------------
// normalize: out[s][h*64+d] *= trace[h][d][d] / lsum[h][s]
// ---------------------------------------------------------------------------
__global__ __launch_bounds__(256) void norm_out(
    float* __restrict__ out, const float* __restrict__ lsum,
    const float* __restrict__ trace)
{
    int g = blockIdx.x * 256 + threadIdx.x;   // 0 .. 1048575
    int base = g * 4;
    int s = base >> 10;
    int e = base & 1023;
    int h = e >> 6, d0 = e & 63;
    float invl = 1.0f / lsum[h * S_LEN + s];
    float4 v = *(float4*)(out + base);
    v.x *= invl * trace[h * 4096 + (d0 + 0) * 65];
    v.y *= invl * trace[h * 4096 + (d0 + 1) * 65];
    v.z *= invl * trace[h * 4096 + (d0 + 2) * 65];
    v.w *= invl * trace[h * 4096 + (d0 + 3) * 65];
    *(float4*)(out + base) = v;
}

extern "C" void kernel_launch(void* const* d_in, const int* in_sizes, int n_in,
                              void* d_out, int out_size, void* d_ws, size_t ws_size,
                              hipStream_t stream) {
    const float* X     = (const float*)d_in[0];   // [1,4096,1024]
    const float* W     = (const float*)d_in[1];   // [3072,1024]
    const float* bias  = (const float*)d_in[2];   // [3072]
    const float* trace = (const float*)d_in[3];   // [16,64,64]
    float* out = (float*)d_out;

    unsigned short* Qb = (unsigned short*)d_ws;            // 8 MiB [h][s][d] (pre-scaled)
    unsigned short* Kb = Qb + 4194304;                     // 8 MiB [h][s][d]
    unsigned short* Vt = Kb + 4194304;                     // 8 MiB [h][d][s]
    float*          ls = (float*)(Vt + 4194304);           // 256 KiB l sums
    unsigned short* Xb = (unsigned short*)(ls + 65536);    // 8 MiB bf16 X
    unsigned short* Wb = Xb + 4194304;                     // 6 MiB bf16 W

    const size_t NEED_BF16 = (size_t)3 * 8388608 + 262144 + 8388608 + 6291456;
    const size_t NEED_F32  = (size_t)3 * 8388608 + 262144;

    hipMemsetAsync(d_out, 0, (size_t)out_size * 4, stream);
    hipMemsetAsync(ls, 0, 65536 * 4, stream);

    if (ws_size >= NEED_BF16) {
        cvt_bf16<<<3584, 256, 0, stream>>>(X, W, Xb, Wb);
        qkv_gemm_bf16<<<768, 256, 0, stream>>>(Xb, Wb, bias, Qb, Kb, Vt);
    } else {
        (void)NEED_F32;
        qkv_gemm_f32<<<dim3(24, 32), 256, 0, stream>>>(X, W, bias, Qb, Kb, Vt);
    }
    attn<<<1024, 256, 0, stream>>>(Qb, Kb, Vt, out, ls);
    norm_out<<<4096, 256, 0, stream>>>(out, ls, trace);
}

// Round 4
// 213.293 us; speedup vs baseline: 1.4420x; 1.4420x over previous
//
#include <hip/hip_runtime.h>
#include <hip/hip_bf16.h>
#include <stdint.h>

#define S_LEN 4096

typedef short s16x8  __attribute__((ext_vector_type(8)));
typedef float f32x4  __attribute__((ext_vector_type(4)));
typedef float f32x16 __attribute__((ext_vector_type(16)));

// log2(e)/8 : folded into Q at QKV epilogue; attn does exp2(score) directly
#define CEXP 0.18033688011112042f

__device__ __forceinline__ unsigned short f2bf(float f) {
    union { float f; unsigned u; } v; v.f = f;
    unsigned r = v.u + 0x7fffu + ((v.u >> 16) & 1u);
    return (unsigned short)(r >> 16);
}

__device__ __forceinline__ ushort2 pkbf(float a, float b) {
    float2 f; f.x = a; f.y = b;
    __hip_bfloat162 h = __float22bfloat162_rn(f);
    union { __hip_bfloat162 h; ushort2 u; } cv; cv.h = h;
    return cv.u;
}

__device__ __forceinline__ ushort4 pkbf4(float x, float y, float z, float w) {
    ushort2 lo = pkbf(x, y), hi = pkbf(z, w);
    ushort4 r; r.x = lo.x; r.y = lo.y; r.z = hi.x; r.w = hi.y;
    return r;
}

typedef const __attribute__((address_space(1))) void* gas_t;
typedef __attribute__((address_space(3))) void* sas_t;

__device__ __forceinline__ void async16(const void* g, void* s) {
    __builtin_amdgcn_global_load_lds((gas_t)g, (sas_t)s, 16, 0, 0);
}

// ---------------------------------------------------------------------------
// fp32 -> bf16 convert for X (4194304) and W (3145728). 8 elems/thread.
// ---------------------------------------------------------------------------
__global__ __launch_bounds__(256) void cvt_bf16(
    const float* __restrict__ X, const float* __restrict__ W,
    unsigned short* __restrict__ Xb, unsigned short* __restrict__ Wb)
{
    const long NX = 4194304;
    long i = (long)(blockIdx.x * 256 + threadIdx.x) * 8;
    const float* src; unsigned short* dst; long off;
    if (i < NX) { src = X; dst = Xb; off = i; }
    else        { src = W; dst = Wb; off = i - NX; }
    float4 a = *(const float4*)(src + off);
    float4 b = *(const float4*)(src + off + 4);
    union { s16x8 v; ushort4 q[2]; } o;
    o.q[0] = pkbf4(a.x, a.y, a.z, a.w);
    o.q[1] = pkbf4(b.x, b.y, b.z, b.w);
    *(s16x8*)(dst + off) = o.v;
}

// ---------------------------------------------------------------------------
// Kernel A (primary): qkv = Xb @ Wb^T + b, bf16 in, m97-style staging.
// 128x128 tile, BK=64, global_load_lds width-16, mfma 16x16x32.
// Q pre-scaled by CEXP; V columns pre-scaled by trace diagonal (exact:
// (P.V)*t == P.(V*t)). Q,K -> [h][s][d]; V -> transposed [h][d][s].
// ---------------------------------------------------------------------------
__global__ __launch_bounds__(256) void qkv_gemm_bf16(
    const unsigned short* __restrict__ Xb, const unsigned short* __restrict__ Wb,
    const float* __restrict__ bias, const float* __restrict__ trace,
    unsigned short* __restrict__ Qb, unsigned short* __restrict__ Kb,
    unsigned short* __restrict__ Vt)
{
    __shared__ __align__(16) unsigned short sm[17408];   // 34816 B
    unsigned short* As = sm;            // [128][64] bf16, unpadded (async dst)
    unsigned short* Bs = sm + 8192;     // [128][64]

    const int t = threadIdx.x;
    const int l = t & 63;
    const int w = t >> 6;
    const int bm = blockIdx.y, bn = blockIdx.x;
    const int rowBase = (w >> 1) * 64;
    const int colBase = (w & 1) * 64;

    f32x4 acc[4][4];
#pragma unroll
    for (int i = 0; i < 4; i++)
#pragma unroll
        for (int j = 0; j < 4; j++) acc[i][j] = (f32x4)0.f;

    const int srow = l >> 3;        // 0..7
    const int scol = (l & 7) * 8;   // shorts

    for (int kt = 0; kt < 16; ++kt) {
        const int k0 = kt * 64;
#pragma unroll
        for (int c = 0; c < 4; ++c) {
            int m = w * 4 + c;                    // chunk 0..15 (8 rows each)
            const unsigned short* ga = Xb + (bm * 128 + m * 8 + srow) * 1024 + k0 + scol;
            const unsigned short* gb = Wb + (bn * 128 + m * 8 + srow) * 1024 + k0 + scol;
            async16(ga, As + m * 512);
            async16(gb, Bs + m * 512);
        }
        __syncthreads();

#pragma unroll
        for (int kc = 0; kc < 2; ++kc) {
            s16x8 af[4], bf[4];
#pragma unroll
            for (int i = 0; i < 4; i++) {
                af[i] = *(const s16x8*)(As + (rowBase + i * 16 + (l & 15)) * 64 + kc * 32 + (l >> 4) * 8);
                bf[i] = *(const s16x8*)(Bs + (colBase + i * 16 + (l & 15)) * 64 + kc * 32 + (l >> 4) * 8);
            }
#pragma unroll
            for (int i = 0; i < 4; i++)
#pragma unroll
                for (int j = 0; j < 4; j++)
                    acc[i][j] = __builtin_amdgcn_mfma_f32_16x16x32_bf16(af[i], bf[j], acc[i][j], 0, 0, 0);
        }
        __syncthreads();
    }

    if (bn < 16) {
#pragma unroll
        for (int j = 0; j < 4; j++) {
            int col = bn * 128 + colBase + j * 16 + (l & 15);
            float bv = bias[col];
            int region = col >> 10;            // 0=Q, 1=K
            int within = col & 1023;
            int h = within >> 6, d = within & 63;
            unsigned short* dst = (region == 0) ? Qb : Kb;
            float scl = (region == 0) ? CEXP : 1.0f;
#pragma unroll
            for (int i = 0; i < 4; i++) {
                int s0 = bm * 128 + rowBase + i * 16 + ((l >> 4) << 2);
#pragma unroll
                for (int r = 0; r < 4; r++)
                    dst[(h * S_LEN + s0 + r) * 64 + d] = f2bf((acc[i][j][r] + bv) * scl);
            }
        }
    } else {
        __syncthreads();
        unsigned short* Lt = sm;              // 128 x 136
#pragma unroll
        for (int j = 0; j < 4; j++) {
            int cl = colBase + j * 16 + (l & 15);
            int o  = bn * 128 + cl - 2048;     // 0..1023 within V
            float bv = bias[bn * 128 + cl];
            float tr = trace[(o >> 6) * 4096 + (o & 63) * 65];
#pragma unroll
            for (int i = 0; i < 4; i++) {
                int s0 = rowBase + i * 16 + ((l >> 4) << 2);
                *(ushort4*)(Lt + cl * 136 + s0) =
                    pkbf4((acc[i][j][0] + bv) * tr, (acc[i][j][1] + bv) * tr,
                          (acc[i][j][2] + bv) * tr, (acc[i][j][3] + bv) * tr);
            }
        }
        __syncthreads();
#pragma unroll
        for (int p = 0; p < 8; ++p) {
            int dl  = (t >> 4) + p * 16;
            int sch = (t & 15) * 8;
            int o = bn * 128 + dl - 2048;
            int h = o >> 6, d = o & 63;
            s16x8 v = *(const s16x8*)(Lt + dl * 136 + sch);
            *(s16x8*)(Vt + (h * 64 + d) * S_LEN + bm * 128 + sch) = v;
        }
    }
}

// ---------------------------------------------------------------------------
// Kernel A (fallback, small ws): fp32-staged GEMM, same outputs
// ---------------------------------------------------------------------------
__global__ __launch_bounds__(256) void qkv_gemm_f32(
    const float* __restrict__ X, const float* __restrict__ W,
    const float* __restrict__ bias, const float* __restrict__ trace,
    unsigned short* __restrict__ Qb, unsigned short* __restrict__ Kb,
    unsigned short* __restrict__ Vt)
{
    __shared__ __align__(16) unsigned short sm[17408];
    unsigned short* As = sm;
    unsigned short* Bs = sm + 5120;

    const int t = threadIdx.x;
    const int l = t & 63;
    const int w = t >> 6;
    const int bm = blockIdx.y, bn = blockIdx.x;
    const int rowBase = (w >> 1) * 64;
    const int colBase = (w & 1) * 64;

    f32x4 acc[4][4];
#pragma unroll
    for (int i = 0; i < 4; i++)
#pragma unroll
        for (int j = 0; j < 4; j++) acc[i][j] = (f32x4)0.f;

    const int sr = t >> 3;
    const int sc = (t & 7) * 4;

    for (int kt = 0; kt < 32; ++kt) {
        const int k0 = kt * 32;
#pragma unroll
        for (int p = 0; p < 4; ++p) {
            int r = sr + p * 32;
            float4 xa = *(const float4*)(X + (bm * 128 + r) * 1024 + k0 + sc);
            float4 wb = *(const float4*)(W + (bn * 128 + r) * 1024 + k0 + sc);
            *(ushort4*)(As + r * 40 + sc) = pkbf4(xa.x, xa.y, xa.z, xa.w);
            *(ushort4*)(Bs + r * 40 + sc) = pkbf4(wb.x, wb.y, wb.z, wb.w);
        }
        __syncthreads();

        s16x8 af[4], bf[4];
#pragma unroll
        for (int i = 0; i < 4; i++) {
            af[i] = *(const s16x8*)(As + (rowBase + i * 16 + (l & 15)) * 40 + (l >> 4) * 8);
            bf[i] = *(const s16x8*)(Bs + (colBase + i * 16 + (l & 15)) * 40 + (l >> 4) * 8);
        }
#pragma unroll
        for (int i = 0; i < 4; i++)
#pragma unroll
            for (int j = 0; j < 4; j++)
                acc[i][j] = __builtin_amdgcn_mfma_f32_16x16x32_bf16(af[i], bf[j], acc[i][j], 0, 0, 0);
        __syncthreads();
    }

    if (bn < 16) {
#pragma unroll
        for (int j = 0; j < 4; j++) {
            int col = bn * 128 + colBase + j * 16 + (l & 15);
            float bv = bias[col];
            int region = col >> 10;
            int within = col & 1023;
            int h = within >> 6, d = within & 63;
            unsigned short* dst = (region == 0) ? Qb : Kb;
            float scl = (region == 0) ? CEXP : 1.0f;
#pragma unroll
            for (int i = 0; i < 4; i++) {
                int s0 = bm * 128 + rowBase + i * 16 + ((l >> 4) << 2);
#pragma unroll
                for (int r = 0; r < 4; r++)
                    dst[(h * S_LEN + s0 + r) * 64 + d] = f2bf((acc[i][j][r] + bv) * scl);
            }
        }
    } else {
        __syncthreads();
        unsigned short* Lt = sm;
#pragma unroll
        for (int j = 0; j < 4; j++) {
            int cl = colBase + j * 16 + (l & 15);
            int o  = bn * 128 + cl - 2048;
            float bv = bias[bn * 128 + cl];
            float tr = trace[(o >> 6) * 4096 + (o & 63) * 65];
#pragma unroll
            for (int i = 0; i < 4; i++) {
                int s0 = rowBase + i * 16 + ((l >> 4) << 2);
                *(ushort4*)(Lt + cl * 136 + s0) =
                    pkbf4((acc[i][j][0] + bv) * tr, (acc[i][j][1] + bv) * tr,
                          (acc[i][j][2] + bv) * tr, (acc[i][j][3] + bv) * tr);
            }
        }
        __syncthreads();
#pragma unroll
        for (int p = 0; p < 8; ++p) {
            int dl  = (t >> 4) + p * 16;
            int sch = (t & 15) * 8;
            int o = bn * 128 + dl - 2048;
            int h = o >> 6, d = o & 63;
            s16x8 v = *(const s16x8*)(Lt + dl * 136 + sch);
            *(s16x8*)(Vt + (h * 64 + d) * S_LEN + bm * 128 + sch) = v;
        }
    }
}

// ---------------------------------------------------------------------------
// Kernel B: flash attention, S^T trick, fixed m=0, IN-BLOCK kv-split:
// 512 threads = 2 wave-groups x 4 waves; group g covers kv half g of the
// same 128-q tile. O and l are plain sums (m=0) -> combine through LDS at
// the end. 2 blocks/CU x 8 waves = 16 waves/CU, no atomics, no extra HBM.
// V already carries the trace diagonal; output needs only 1/l.
// ---------------------------------------------------------------------------
__global__ __launch_bounds__(512, 4) void attn(
    const unsigned short* __restrict__ Qb, const unsigned short* __restrict__ Kb,
    const unsigned short* __restrict__ Vt, float* __restrict__ out)
{
    __shared__ __align__(16) unsigned short sm[35840];   // 71680 B
    __shared__ float lArr[256];
    // per-group: Ks 64x72 [kv][d], Vts 64x72 [d][kv]
    // Ps: 8 waves x 32 x 68 [q][kv] at offset 18432

    const int t = threadIdx.x;
    const int l = t & 63;
    const int w = t >> 6;            // 0..7
    const int g = w >> 2;            // kv half
    const int wq = w & 3;            // q sub-tile
    const int h = blockIdx.y;
    const int qbase = blockIdx.x * 128 + wq * 32;
    const int l31 = l & 31;
    const int lh  = l >> 5;

    unsigned short* Ks  = sm + g * 9216;
    unsigned short* Vts = sm + g * 9216 + 4608;
    unsigned short* Pw  = sm + 18432 + w * 2176 + l31 * 68;

    s16x8 qf[4];
#pragma unroll
    for (int ks = 0; ks < 4; ks++)
        qf[ks] = *(const s16x8*)(Qb + (h * S_LEN + qbase + l31) * 64 + ks * 16 + lh * 8);

    f32x16 O0 = (f32x16)0.f, O1 = (f32x16)0.f;
    float lp0 = 0.f, lp1 = 0.f, lp2 = 0.f, lp3 = 0.f;

    const int tg    = t & 255;           // position within group
    const int strow = tg >> 2;           // 0..63
    const int stch  = (tg & 3) * 16;

    for (int kt = 0; kt < 32; ++kt) {
        const int kv0 = g * 2048 + kt * 64;
        {
            const unsigned short* ksrc = Kb + (h * S_LEN + kv0 + strow) * 64 + stch;
            const unsigned short* vsrc = Vt + (h * 64 + strow) * S_LEN + kv0 + stch;
            s16x8 k0v = *(const s16x8*)(ksrc);
            s16x8 k1v = *(const s16x8*)(ksrc + 8);
            s16x8 v0v = *(const s16x8*)(vsrc);
            s16x8 v1v = *(const s16x8*)(vsrc + 8);
            *(s16x8*)(Ks  + strow * 72 + stch)     = k0v;
            *(s16x8*)(Ks  + strow * 72 + stch + 8) = k1v;
            *(s16x8*)(Vts + strow * 72 + stch)     = v0v;
            *(s16x8*)(Vts + strow * 72 + stch + 8) = v1v;
        }
        __syncthreads();

        // S^T[kv][q] = K x Q^T  (scores pre-scaled via Q)
        f32x16 S0 = (f32x16)0.f, S1 = (f32x16)0.f;
#pragma unroll
        for (int ks = 0; ks < 4; ks++) {
            s16x8 a0 = *(const s16x8*)(Ks + l31 * 72 + ks * 16 + lh * 8);
            s16x8 a1 = *(const s16x8*)(Ks + (32 + l31) * 72 + ks * 16 + lh * 8);
            S0 = __builtin_amdgcn_mfma_f32_32x32x16_bf16(a0, qf[ks], S0, 0, 0, 0);
            S1 = __builtin_amdgcn_mfma_f32_32x32x16_bf16(a1, qf[ks], S1, 0, 0, 0);
        }

#pragma unroll
        for (int i = 0; i < 16; i += 4) {
            float p0 = __builtin_amdgcn_exp2f(S0[i+0]); S0[i+0] = p0; lp0 += p0;
            float p1 = __builtin_amdgcn_exp2f(S0[i+1]); S0[i+1] = p1; lp1 += p1;
            float p2 = __builtin_amdgcn_exp2f(S0[i+2]); S0[i+2] = p2; lp2 += p2;
            float p3 = __builtin_amdgcn_exp2f(S0[i+3]); S0[i+3] = p3; lp3 += p3;
        }
#pragma unroll
        for (int i = 0; i < 16; i += 4) {
            float p0 = __builtin_amdgcn_exp2f(S1[i+0]); S1[i+0] = p0; lp0 += p0;
            float p1 = __builtin_amdgcn_exp2f(S1[i+1]); S1[i+1] = p1; lp1 += p1;
            float p2 = __builtin_amdgcn_exp2f(S1[i+2]); S1[i+2] = p2; lp2 += p2;
            float p3 = __builtin_amdgcn_exp2f(S1[i+3]); S1[i+3] = p3; lp3 += p3;
        }

#pragma unroll
        for (int gq = 0; gq < 4; ++gq) {
            *(ushort4*)(Pw + gq * 8 + lh * 4)      = pkbf4(S0[gq*4], S0[gq*4+1], S0[gq*4+2], S0[gq*4+3]);
            *(ushort4*)(Pw + 32 + gq * 8 + lh * 4) = pkbf4(S1[gq*4], S1[gq*4+1], S1[gq*4+2], S1[gq*4+3]);
        }

#pragma unroll
        for (int ks = 0; ks < 4; ks++) {
            union { s16x8 v; ushort4 q[2]; } pu;
            pu.q[0] = *(const ushort4*)(Pw + ks * 16 + lh * 8);
            pu.q[1] = *(const ushort4*)(Pw + ks * 16 + lh * 8 + 4);
            s16x8 av0 = *(const s16x8*)(Vts + l31 * 72 + ks * 16 + lh * 8);
            s16x8 av1 = *(const s16x8*)(Vts + (32 + l31) * 72 + ks * 16 + lh * 8);
            O0 = __builtin_amdgcn_mfma_f32_32x32x16_bf16(av0, pu.v, O0, 0, 0, 0);
            O1 = __builtin_amdgcn_mfma_f32_32x32x16_bf16(av1, pu.v, O1, 0, 0, 0);
        }
        __syncthreads();
    }

    // per-wave l partial for q = qbase + l31
    float l_part = (lp0 + lp1) + (lp2 + lp3);
    float l_tot = l_part + __shfl_xor(l_part, 32);
    if (lh == 0) lArr[w * 32 + l31] = l_tot;

    // stash raw O^T (fp32) per wave: Lo[w][q 0..31][d 0..67(pad)]
    float* Lo = (float*)sm + w * 2176;
#pragma unroll
    for (int dt = 0; dt < 2; ++dt) {
        const f32x16& Ox = dt ? O1 : O0;
#pragma unroll
        for (int gq = 0; gq < 4; ++gq) {
            int d0 = dt * 32 + gq * 8 + lh * 4;
            float4 vv;
            vv.x = Ox[gq*4+0]; vv.y = Ox[gq*4+1]; vv.z = Ox[gq*4+2]; vv.w = Ox[gq*4+3];
            *(float4*)(Lo + l31 * 68 + d0) = vv;
        }
    }
    __syncthreads();

    // waves 0-3: combine the two kv-half partials, normalize, store
    if (w < 4) {
        const float* LoA = (float*)sm + w * 2176;
        const float* LoB = (float*)sm + (w + 4) * 2176;
#pragma unroll
        for (int it = 0; it < 8; ++it) {
            int ql = it * 4 + (l >> 4);
            float invl = 1.0f / (lArr[w * 32 + ql] + lArr[(w + 4) * 32 + ql]);
            float4 a = *(const float4*)(LoA + ql * 68 + (l & 15) * 4);
            float4 b = *(const float4*)(LoB + ql * 68 + (l & 15) * 4);
            float4 vv;
            vv.x = (a.x + b.x) * invl;
            vv.y = (a.y + b.y) * invl;
            vv.z = (a.z + b.z) * invl;
            vv.w = (a.w + b.w) * invl;
            *(float4*)(out + (blockIdx.x * 128 + w * 32 + ql) * 1024 + h * 64 + (l & 15) * 4) = vv;
        }
    }
}

extern "C" void kernel_launch(void* const* d_in, const int* in_sizes, int n_in,
                              void* d_out, int out_size, void* d_ws, size_t ws_size,
                              hipStream_t stream) {
    const float* X     = (const float*)d_in[0];   // [1,4096,1024]
    const float* W     = (const float*)d_in[1];   // [3072,1024]
    const float* bias  = (const float*)d_in[2];   // [3072]
    const float* trace = (const float*)d_in[3];   // [16,64,64]
    float* out = (float*)d_out;

    unsigned short* Qb = (unsigned short*)d_ws;            // 8 MiB [h][s][d] (pre-scaled by CEXP)
    unsigned short* Kb = Qb + 4194304;                     // 8 MiB [h][s][d]
    unsigned short* Vt = Kb + 4194304;                     // 8 MiB [h][d][s] (pre-scaled by trace diag)
    unsigned short* Xb = Vt + 4194304;                     // 8 MiB bf16 X
    unsigned short* Wb = Xb + 4194304;                     // 6 MiB bf16 W

    const size_t NEED_BF16 = (size_t)3 * 8388608 + 8388608 + 6291456;

    if (ws_size >= NEED_BF16) {
        cvt_bf16<<<3584, 256, 0, stream>>>(X, W, Xb, Wb);
        qkv_gemm_bf16<<<dim3(24, 32), 256, 0, stream>>>(Xb, Wb, bias, trace, Qb, Kb, Vt);
    } else {
        qkv_gemm_f32<<<dim3(24, 32), 256, 0, stream>>>(X, W, bias, trace, Qb, Kb, Vt);
    }
    attn<<<dim3(32, 16), 512, 0, stream>>>(Qb, Kb, Vt, out);
}